// Round 12
// baseline (161.776 us; speedup 1.0000x reference)
//
#include <hip/hip_runtime.h>
#include <math.h>

#define B_  8
#define H_  8
#define C_  512
#define L_  1024
#define DH  64
#define WIN 4

typedef __attribute__((ext_vector_type(8))) short short8;
typedef __attribute__((ext_vector_type(4))) float floatx4;

__device__ __forceinline__ unsigned short f2bf(float f) {
    unsigned int u = __float_as_uint(f);
    u = u + 0x7FFFu + ((u >> 16) & 1u);     // RNE
    return (unsigned short)(u >> 16);
}
__device__ __forceinline__ float bf2f(unsigned short h) {
    return __uint_as_float(((unsigned int)h) << 16);
}
__device__ __forceinline__ unsigned short f2h(float f) {
    _Float16 h = (_Float16)f;
    return *reinterpret_cast<unsigned short*>(&h);
}

// async global->LDS, 16B per lane; dest = wave-uniform base + lane*16
__device__ __forceinline__ void gload_lds16(const void* g, void* l) {
    __builtin_amdgcn_global_load_lds(
        (const __attribute__((address_space(1))) void*)g,
        (__attribute__((address_space(3))) void*)l, 16, 0, 0);
}

// ---------------------------------------------------------------------------
// Merged prep + transpose.
// Blocks [0,4096): x (B,C,L) fp32 -> xT bf16 (B,L,C), 32x32 LDS transpose.
// Blocks [4096,4352): W conversions + bias pack.
// ---------------------------------------------------------------------------
__global__ __launch_bounds__(256) void prep_transpose_kernel(
    const float* __restrict__ x,
    const float* __restrict__ Wq, const float* __restrict__ Wk,
    const float* __restrict__ Wv, const float* __restrict__ Wo,
    const float* __restrict__ bq, const float* __restrict__ bk,
    const float* __restrict__ bv,
    unsigned short* __restrict__ xT,
    unsigned short* __restrict__ Wqkv_hi,
    unsigned short* __restrict__ Wo_h,
    float* __restrict__ bqkv)
{
    __shared__ float tile[32][33];
    const int bid = blockIdx.x;
    const int t   = threadIdx.x;

    if (bid < 4096) {
        const int b  = bid >> 9;
        const int cb = ((bid >> 5) & 15) * 32;
        const int lb = (bid & 31) * 32;
        {
            const int l = t & 31, c0 = t >> 5;
#pragma unroll
            for (int p = 0; p < 4; ++p) {
                const int c = c0 + 8 * p;
                tile[c][l] = x[((size_t)b * C_ + cb + c) * L_ + lb + l];
            }
        }
        __syncthreads();
        {
            const int c = t & 31, l0 = t >> 5;
#pragma unroll
            for (int p = 0; p < 4; ++p) {
                const int l = l0 + 8 * p;
                xT[((size_t)b * L_ + lb + l) * C_ + cb + c] = f2bf(tile[c][l]);
            }
        }
    } else {
        const int i = (bid - 4096) * 256 + t;   // 65536 float4 slots
        float4 v; ushort4 h;

        v = ((const float4*)Wq)[i];
        h.x = f2bf(v.x); h.y = f2bf(v.y); h.z = f2bf(v.z); h.w = f2bf(v.w);
        ((ushort4*)Wqkv_hi)[i] = h;

        v = ((const float4*)Wk)[i];
        h.x = f2bf(v.x); h.y = f2bf(v.y); h.z = f2bf(v.z); h.w = f2bf(v.w);
        ((ushort4*)Wqkv_hi)[65536 + i] = h;

        v = ((const float4*)Wv)[i];
        h.x = f2bf(v.x); h.y = f2bf(v.y); h.z = f2bf(v.z); h.w = f2bf(v.w);
        ((ushort4*)Wqkv_hi)[131072 + i] = h;

        v = ((const float4*)Wo)[i];
        h.x = f2h(v.x); h.y = f2h(v.y); h.z = f2h(v.z); h.w = f2h(v.w);
        ((ushort4*)Wo_h)[i] = h;

        if (i < 512)       bqkv[i] = bq[i];
        else if (i < 1024) bqkv[i] = bk[i - 512];
        else if (i < 1536) bqkv[i] = bv[i - 1024];
    }
}

// ---------------------------------------------------------------------------
// Fused QKV GEMM v3 (measured optimum): global_load_lds staging, linear LDS
// [128][32], one barrier per K-step, 4 waves.  Epilogue sT[128][144]
// aliases SM.
// ---------------------------------------------------------------------------
__global__ __launch_bounds__(256) void qkv_gemm_kernel(
    const unsigned short* __restrict__ Wh, const float* __restrict__ bqkv,
    const unsigned short* __restrict__ xT,
    unsigned short* __restrict__ Qb, unsigned short* __restrict__ Kb,
    unsigned short* __restrict__ Vc)
{
    __shared__ __align__(16) unsigned short SM[18432];

    const int b   = blockIdx.z;
    const int oB  = blockIdx.y * 128;
    const int mat = oB >> 9;                // 0=Q,1=K,2=V
    const int ob  = oB & 511;
    const int lb  = blockIdx.x * 128;
    const int t  = threadIdx.x;
    const int w = t >> 6, lane = t & 63, quad = lane >> 4, lc = lane & 15;
    const int wm = w >> 1, wn = w & 1;

    const unsigned short* Wm = Wh + (size_t)mat * C_ * C_;

    floatx4 acc[4][4];
#pragma unroll
    for (int i = 0; i < 4; ++i)
#pragma unroll
        for (int j = 0; j < 4; ++j) acc[i][j] = (floatx4)0.f;

    const int srow = w * 32 + (lane >> 2);      // staging row (+16 for p=1)
    const int sc8  = (lane & 3) * 8;            // staging col (elements)

#define QKV_STAGE(BUF, S) {                                                  \
    const int c0_ = (S) * 32;                                                \
    _Pragma("unroll")                                                        \
    for (int p_ = 0; p_ < 2; ++p_) {                                         \
        gload_lds16(&Wm[(size_t)(ob + srow + 16 * p_) * C_ + c0_ + sc8],     \
                    &SM[(0 * 2 + (BUF)) * 4096 + (w * 32 + p_ * 16) * 32]);  \
        gload_lds16(&xT[((size_t)b * L_ + lb + srow + 16 * p_) * C_ + c0_ + sc8], \
                    &SM[(1 * 2 + (BUF)) * 4096 + (w * 32 + p_ * 16) * 32]);  \
    }                                                                        \
}

    QKV_STAGE(0, 0)
    __syncthreads();

    for (int s = 0; s < 16; ++s) {
        const int cur = s & 1;
        if (s < 15) QKV_STAGE(1 - cur, s + 1)

        const unsigned short (*At)[32] =
            reinterpret_cast<const unsigned short (*)[32]>(&SM[(0 * 2 + cur) * 4096]);
        const unsigned short (*Bt)[32] =
            reinterpret_cast<const unsigned short (*)[32]>(&SM[(1 * 2 + cur) * 4096]);

        short8 a[4], bb[4];
#pragma unroll
        for (int mt = 0; mt < 4; ++mt)
            a[mt] = *reinterpret_cast<const short8*>(&At[wm * 64 + mt * 16 + lc][quad * 8]);
#pragma unroll
        for (int nt = 0; nt < 4; ++nt)
            bb[nt] = *reinterpret_cast<const short8*>(&Bt[wn * 64 + nt * 16 + lc][quad * 8]);
#pragma unroll
        for (int mt = 0; mt < 4; ++mt)
#pragma unroll
            for (int nt = 0; nt < 4; ++nt)
                acc[mt][nt] = __builtin_amdgcn_mfma_f32_16x16x32_bf16(
                    a[mt], bb[nt], acc[mt][nt], 0, 0, 0);

        __syncthreads();
    }

    if (mat == 2) {
#pragma unroll
        for (int mt = 0; mt < 4; ++mt) {
#pragma unroll
            for (int r = 0; r < 4; ++r) {
                const int o  = ob + wm * 64 + mt * 16 + quad * 4 + r;
                const float bi = bqkv[1024 + o];
#pragma unroll
                for (int nt = 0; nt < 4; ++nt) {
                    const int l = lb + wn * 64 + nt * 16 + lc;
                    Vc[((size_t)b * C_ + o) * L_ + l] = f2bf(acc[mt][nt][r] + bi);
                }
            }
        }
    } else {
        const float scale = (mat == 0) ? 0.125f : 1.0f;
        unsigned short* dst = (mat == 0) ? Qb : Kb;
        unsigned short (*sT)[144] =
            reinterpret_cast<unsigned short (*)[144]>(&SM[0]);

#pragma unroll
        for (int mt = 0; mt < 4; ++mt) {
#pragma unroll
            for (int r = 0; r < 4; ++r) {
                const int o  = ob + wm * 64 + mt * 16 + quad * 4 + r;
                const float bi = bqkv[mat * 512 + o];
                const int d  = mt * 16 + quad * 4 + r;
#pragma unroll
                for (int nt = 0; nt < 4; ++nt) {
                    const int l = wn * 64 + nt * 16 + lc;
                    sT[l][wm * 72 + d] = f2bf((acc[mt][nt][r] + bi) * scale);
                }
            }
        }
        __syncthreads();
        {
            const int l = t >> 1, hf = t & 1;
#pragma unroll
            for (int h01 = 0; h01 < 2; ++h01) {
                const int hgl = (ob >> 6) + h01;
                const size_t o = (((size_t)b * H_ + hgl) * L_ + lb + l) * DH + hf * 32;
                const int cbase = h01 * 72 + hf * 32;
                uint4 v0 = *reinterpret_cast<const uint4*>(&sT[l][cbase]);
                uint4 v1 = *reinterpret_cast<const uint4*>(&sT[l][cbase + 8]);
                uint4 v2 = *reinterpret_cast<const uint4*>(&sT[l][cbase + 16]);
                uint4 v3 = *reinterpret_cast<const uint4*>(&sT[l][cbase + 24]);
                *reinterpret_cast<uint4*>(&dst[o])      = v0;
                *reinterpret_cast<uint4*>(&dst[o + 8])  = v1;
                *reinterpret_cast<uint4*>(&dst[o + 16]) = v2;
                *reinterpret_cast<uint4*>(&dst[o + 24]) = v3;
            }
        }
    }
}

// ---------------------------------------------------------------------------
// Attention v15 (unchanged — measured best): v13a 2-group + s_setprio.
// ---------------------------------------------------------------------------
__global__ __launch_bounds__(256, 2) void attn_kernel15(
    const unsigned short* __restrict__ Qb,   // bf16 (B,H,L,Dh), pre-scaled
    const unsigned short* __restrict__ Kb,   // bf16 (B,H,L,Dh)
    const unsigned short* __restrict__ Vc,   // bf16 (B,C,L)
    const float* __restrict__ erel_k, const float* __restrict__ erel_v,
    unsigned short* __restrict__ AOh)        // f16 (B,L,C)
{
    __shared__ __align__(16) unsigned short kst[2][64][68];   // 17408 B
    __shared__ __align__(16) unsigned short vst[2][64][68];   // 17408 B
    __shared__ __align__(16) unsigned short Pl[4][2][16][68]; // 17408 B
    __shared__ float rs[128][9];                              //  4608 B
    __shared__ float rv[128][9];                              //  4608 B

    const int t  = threadIdx.x;
    const int bh = blockIdx.x;          // 0..63  (id%8==h -> XCD L2 locality)
    const int rt = blockIdx.y;          // 0..7
    const int b = bh >> 3, h = bh & 7;
    const int w = t >> 6, lane = t & 63, quad = lane >> 4, lc = lane & 15;
    const int rowB = rt * 128 + w * 32; // wave's 32 rows; group g: rowB+g*16

    const size_t qkBase = (size_t)bh * L_ * DH;
    const size_t vBase  = ((size_t)b * C_ + h * DH) * L_;

    for (int i = lane; i < 32 * 9; i += 64) rv[w * 32 + i / 9][i % 9] = 0.f;

    // Q A-fragments for both groups
    short8 af0[2], af1[2];
#pragma unroll
    for (int kk = 0; kk < 2; ++kk) {
        af0[kk] = *reinterpret_cast<const short8*>(
            &Qb[qkBase + (size_t)(rowB + lc) * DH + kk * 32 + quad * 8]);
        af1[kk] = *reinterpret_cast<const short8*>(
            &Qb[qkBase + (size_t)(rowB + 16 + lc) * DH + kk * 32 + quad * 8]);
    }

    // rel-k scores via MFMA (bfr built once, shared by both groups)
    {
        floatx4 rsa0 = (floatx4)0.f, rsa1 = (floatx4)0.f;
        const int drow = (lc < 9) ? lc : 8;
#pragma unroll
        for (int kk = 0; kk < 2; ++kk) {
            short8 bfr;
#pragma unroll
            for (int i = 0; i < 8; ++i)
                bfr[i] = (short)f2bf(erel_k[drow * 64 + kk * 32 + quad * 8 + i]);
            rsa0 = __builtin_amdgcn_mfma_f32_16x16x32_bf16(af0[kk], bfr, rsa0, 0, 0, 0);
            rsa1 = __builtin_amdgcn_mfma_f32_16x16x32_bf16(af1[kk], bfr, rsa1, 0, 0, 0);
        }
        if (lc < 9) {
#pragma unroll
            for (int r = 0; r < 4; ++r) {
                rs[w * 32 + quad * 4 + r][lc]      = rsa0[r];
                rs[w * 32 + 16 + quad * 4 + r][lc] = rsa1[r];
            }
        }
    }

    // stage tile 0 (256 thr: 2 uint4 per thread per array covers 64x64)
    const int jr = t >> 2, jcE = (t & 3) * 16;
    *reinterpret_cast<uint4*>(&kst[0][jr][jcE]) =
        *reinterpret_cast<const uint4*>(&Kb[qkBase + (size_t)jr * DH + jcE]);
    *reinterpret_cast<uint4*>(&kst[0][jr][jcE + 8]) =
        *reinterpret_cast<const uint4*>(&Kb[qkBase + (size_t)jr * DH + jcE + 8]);
    *reinterpret_cast<uint4*>(&vst[0][jr][jcE]) =
        *reinterpret_cast<const uint4*>(&Vc[vBase + (size_t)jr * L_ + jcE]);
    *reinterpret_cast<uint4*>(&vst[0][jr][jcE + 8]) =
        *reinterpret_cast<const uint4*>(&Vc[vBase + (size_t)jr * L_ + jcE + 8]);
    __syncthreads();

    short8 ones;
#pragma unroll
    for (int j = 0; j < 8; ++j) ones[j] = (short)0x3F80;

    floatx4 acc_o0[4], acc_o1[4], acc_l0 = (floatx4)0.f, acc_l1 = (floatx4)0.f;
#pragma unroll
    for (int nt = 0; nt < 4; ++nt) { acc_o0[nt] = (floatx4)0.f; acc_o1[nt] = (floatx4)0.f; }

    for (int jt = 0; jt < L_ / 64; ++jt) {
        const int j0  = jt * 64;
        const int cur = jt & 1;

        // register prefetch of next tile (4 uint4)
        uint4 pk0, pk1, pv0, pv1;
        if (jt < L_ / 64 - 1) {
            const int j0n = j0 + 64;
            pk0 = *reinterpret_cast<const uint4*>(
                &Kb[qkBase + (size_t)(j0n + jr) * DH + jcE]);
            pk1 = *reinterpret_cast<const uint4*>(
                &Kb[qkBase + (size_t)(j0n + jr) * DH + jcE + 8]);
            pv0 = *reinterpret_cast<const uint4*>(
                &Vc[vBase + (size_t)jr * L_ + j0n + jcE]);
            pv1 = *reinterpret_cast<const uint4*>(
                &Vc[vBase + (size_t)jr * L_ + j0n + jcE + 8]);
        }

        // S^T = K Q^T for BOTH groups: each kf read feeds 2 MFMAs
        floatx4 s0[4], s1[4];
#pragma unroll
        for (int nt = 0; nt < 4; ++nt) { s0[nt] = (floatx4)0.f; s1[nt] = (floatx4)0.f; }
        __builtin_amdgcn_s_setprio(1);
#pragma unroll
        for (int nt = 0; nt < 4; ++nt)
#pragma unroll
            for (int kk = 0; kk < 2; ++kk) {
                const short8 kf = *reinterpret_cast<const short8*>(
                    &kst[cur][nt * 16 + lc][kk * 32 + quad * 8]);
                s0[nt] = __builtin_amdgcn_mfma_f32_16x16x32_bf16(kf, af0[kk], s0[nt], 0, 0, 0);
                s1[nt] = __builtin_amdgcn_mfma_f32_16x16x32_bf16(kf, af1[kk], s1[nt], 0, 0, 0);
            }
        __builtin_amdgcn_s_setprio(0);

        short8 pf0[2], pf1[2];

        // ---- group 0: bias, exp->Pl[w][0], rv, pf0 ----
        {
            const int rowW = rowB;
            const bool nearD = (j0 <= rowW + 15 + WIN) && (j0 + 63 >= rowW - WIN);
            if (nearD) {
#pragma unroll
                for (int nt = 0; nt < 4; ++nt)
#pragma unroll
                    for (int r = 0; r < 4; ++r) {
                        const int diff = (j0 + nt * 16 + quad * 4 + r) - (rowW + lc);
                        if (diff >= -WIN && diff <= WIN)
                            s0[nt][r] += rs[w * 32 + lc][diff + WIN];
                    }
            }
#pragma unroll
            for (int nt = 0; nt < 4; ++nt) {
                const float e0 = __expf(s0[nt][0]);
                const float e1 = __expf(s0[nt][1]);
                const float e2 = __expf(s0[nt][2]);
                const float e3 = __expf(s0[nt][3]);
                unsigned int u01, u23;
                asm volatile("v_cvt_pk_bf16_f32 %0, %1, %2" : "=v"(u01) : "v"(e0), "v"(e1));
                asm volatile("v_cvt_pk_bf16_f32 %0, %1, %2" : "=v"(u23) : "v"(e2), "v"(e3));
                uint2 pr; pr.x = u01; pr.y = u23;
                *reinterpret_cast<uint2*>(&Pl[w][0][lc][nt * 16 + quad * 4]) = pr;
            }
            if (nearD) {
                for (int idx = lane; idx < 16 * 9; idx += 64) {
                    const int r16 = idx / 9, dr = idx % 9;
                    const int jg = rowW + r16 + dr - WIN;
                    if (jg >= j0 && jg < j0 + 64 && jg >= 0 && jg < L_)
                        rv[w * 32 + r16][dr] += bf2f(Pl[w][0][r16][jg - j0]);
                }
            }
#pragma unroll
            for (int kk = 0; kk < 2; ++kk)
                pf0[kk] = *reinterpret_cast<const short8*>(&Pl[w][0][lc][kk * 32 + quad * 8]);
        }

        // ---- group 1: bias, exp->Pl[w][1] (own buffer), rv, pf1 ----
        {
            const int rowW = rowB + 16;
            const bool nearD = (j0 <= rowW + 15 + WIN) && (j0 + 63 >= rowW - WIN);
            if (nearD) {
#pragma unroll
                for (int nt = 0; nt < 4; ++nt)
#pragma unroll
                    for (int r = 0; r < 4; ++r) {
                        const int diff = (j0 + nt * 16 + quad * 4 + r) - (rowW + lc);
                        if (diff >= -WIN && diff <= WIN)
                            s1[nt][r] += rs[w * 32 + 16 + lc][diff + WIN];
                    }
            }
#pragma unroll
            for (int nt = 0; nt < 4; ++nt) {
                const float e0 = __expf(s1[nt][0]);
                const float e1 = __expf(s1[nt][1]);
                const float e2 = __expf(s1[nt][2]);
                const float e3 = __expf(s1[nt][3]);
                unsigned int u01, u23;
                asm volatile("v_cvt_pk_bf16_f32 %0, %1, %2" : "=v"(u01) : "v"(e0), "v"(e1));
                asm volatile("v_cvt_pk_bf16_f32 %0, %1, %2" : "=v"(u23) : "v"(e2), "v"(e3));
                uint2 pr; pr.x = u01; pr.y = u23;
                *reinterpret_cast<uint2*>(&Pl[w][1][lc][nt * 16 + quad * 4]) = pr;
            }
            if (nearD) {
                for (int idx = lane; idx < 16 * 9; idx += 64) {
                    const int r16 = idx / 9, dr = idx % 9;
                    const int jg = rowW + r16 + dr - WIN;
                    if (jg >= j0 && jg < j0 + 64 && jg >= 0 && jg < L_)
                        rv[w * 32 + 16 + r16][dr] += bf2f(Pl[w][1][r16][jg - j0]);
                }
            }
#pragma unroll
            for (int kk = 0; kk < 2; ++kk)
                pf1[kk] = *reinterpret_cast<const short8*>(&Pl[w][1][lc][kk * 32 + quad * 8]);
        }

        // row sums + PV via MFMA (prioritized cluster)
        __builtin_amdgcn_s_setprio(1);
#pragma unroll
        for (int kk = 0; kk < 2; ++kk) {
            acc_l0 = __builtin_amdgcn_mfma_f32_16x16x32_bf16(pf0[kk], ones, acc_l0, 0, 0, 0);
            acc_l1 = __builtin_amdgcn_mfma_f32_16x16x32_bf16(pf1[kk], ones, acc_l1, 0, 0, 0);
        }
#pragma unroll
        for (int nt = 0; nt < 4; ++nt)
#pragma unroll
            for (int kk = 0; kk < 2; ++kk) {
                const short8 vf = *reinterpret_cast<const short8*>(
                    &vst[cur][nt * 16 + lc][kk * 32 + quad * 8]);
                acc_o0[nt] = __builtin_amdgcn_mfma_f32_16x16x32_bf16(pf0[kk], vf, acc_o0[nt], 0, 0, 0);
                acc_o1[nt] = __builtin_amdgcn_mfma_f32_16x16x32_bf16(pf1[kk], vf, acc_o1[nt], 0, 0, 0);
            }
        __builtin_amdgcn_s_setprio(0);

        // commit prefetched tile, then sync
        if (jt < L_ / 64 - 1) {
            *reinterpret_cast<uint4*>(&kst[1 - cur][jr][jcE])     = pk0;
            *reinterpret_cast<uint4*>(&kst[1 - cur][jr][jcE + 8]) = pk1;
            *reinterpret_cast<uint4*>(&vst[1 - cur][jr][jcE])     = pv0;
            *reinterpret_cast<uint4*>(&vst[1 - cur][jr][jcE + 8]) = pv1;
        }
        __syncthreads();
    }

    // epilogue group 0: rel-v term, normalize, transpose via Pl[w][0], store
    {
#pragma unroll
        for (int nt = 0; nt < 4; ++nt) {
            const int d = nt * 16 + lc;
            float ev[9];
#pragma unroll
            for (int dr = 0; dr < 9; ++dr) ev[dr] = erel_v[dr * 64 + d];
#pragma unroll
            for (int r = 0; r < 4; ++r) {
                const int rloc = w * 32 + quad * 4 + r;
                float v = acc_o0[nt][r];
#pragma unroll
                for (int dr = 0; dr < 9; ++dr) v += rv[rloc][dr] * ev[dr];
                Pl[w][0][quad * 4 + r][nt * 16 + lc] = f2h(v / acc_l0[r]);
            }
        }
        const int row = lane >> 2, ds8 = (lane & 3) * 16;
        const uint4 q0 = *reinterpret_cast<const uint4*>(&Pl[w][0][row][ds8]);
        const uint4 q1 = *reinterpret_cast<const uint4*>(&Pl[w][0][row][ds8 + 8]);
        const size_t o = ((size_t)b * L_ + rowB + row) * C_ + h * 64 + ds8;
        *reinterpret_cast<uint4*>(&AOh[o])     = q0;
        *reinterpret_cast<uint4*>(&AOh[o + 8]) = q1;
    }
    // epilogue group 1
    {
#pragma unroll
        for (int nt = 0; nt < 4; ++nt) {
            const int d = nt * 16 + lc;
            float ev[9];
#pragma unroll
            for (int dr = 0; dr < 9; ++dr) ev[dr] = erel_v[dr * 64 + d];
#pragma unroll
            for (int r = 0; r < 4; ++r) {
                const int rloc = w * 32 + 16 + quad * 4 + r;
                float v = acc_o1[nt][r];
#pragma unroll
                for (int dr = 0; dr < 9; ++dr) v += rv[rloc][dr] * ev[dr];
                Pl[w][1][quad * 4 + r][nt * 16 + lc] = f2h(v / acc_l1[r]);
            }
        }
        const int row = lane >> 2, ds8 = (lane & 3) * 16;
        const uint4 q0 = *reinterpret_cast<const uint4*>(&Pl[w][1][row][ds8]);
        const uint4 q1 = *reinterpret_cast<const uint4*>(&Pl[w][1][row][ds8 + 8]);
        const size_t o = ((size_t)b * L_ + rowB + 16 + row) * C_ + h * 64 + ds8;
        *reinterpret_cast<uint4*>(&AOh[o])     = q0;
        *reinterpret_cast<uint4*>(&AOh[o + 8]) = q1;
    }
}

// ---------------------------------------------------------------------------
// Output projection v4: SAME structure as qkv v3 (the measured-best GEMM
// schedule): 128x128 tile, 4 waves 2x2, acc[4][4], gload_lds staging,
// linear LDS [128][32], one barrier per K-step.  v3's N64 tile had half
// the MFMA:LDS-read ratio and half the per-block work (268 vs 445 TF).
// Epilogue = qkv's V-branch: direct coalesced fp32 store.
// ---------------------------------------------------------------------------
__global__ __launch_bounds__(256) void out_gemm_kernel(
    const unsigned short* __restrict__ Wh,   // f16 512x512
    const float* __restrict__ bo,
    const unsigned short* __restrict__ Ah,   // f16 (B,L,C)
    float* __restrict__ Y)
{
    __shared__ __align__(16) unsigned short SM[16384];  // 4 x [128][32] tiles

    const int b  = blockIdx.z;
    const int ob = blockIdx.y * 128;
    const int lb = blockIdx.x * 128;
    const int t  = threadIdx.x;
    const int w = t >> 6, lane = t & 63, quad = lane >> 4, lc = lane & 15;
    const int wm = w >> 1, wn = w & 1;

    floatx4 acc[4][4];
#pragma unroll
    for (int i = 0; i < 4; ++i)
#pragma unroll
        for (int j = 0; j < 4; ++j) acc[i][j] = (floatx4)0.f;

    const int srow = w * 32 + (lane >> 2);
    const int sc8  = (lane & 3) * 8;

#define OG_STAGE(BUF, S) {                                                   \
    const int c0_ = (S) * 32;                                                \
    _Pragma("unroll")                                                        \
    for (int p_ = 0; p_ < 2; ++p_) {                                         \
        gload_lds16(&Wh[(size_t)(ob + srow + 16 * p_) * C_ + c0_ + sc8],     \
                    &SM[(0 * 2 + (BUF)) * 4096 + (w * 32 + p_ * 16) * 32]);  \
        gload_lds16(&Ah[((size_t)b * L_ + lb + srow + 16 * p_) * C_ + c0_ + sc8], \
                    &SM[(1 * 2 + (BUF)) * 4096 + (w * 32 + p_ * 16) * 32]);  \
    }                                                                        \
}

    OG_STAGE(0, 0)
    __syncthreads();

    for (int s = 0; s < 16; ++s) {
        const int cur = s & 1;
        if (s < 15) OG_STAGE(1 - cur, s + 1)

        const unsigned short (*At)[32] =
            reinterpret_cast<const unsigned short (*)[32]>(&SM[(0 * 2 + cur) * 4096]);
        const unsigned short (*Bt)[32] =
            reinterpret_cast<const unsigned short (*)[32]>(&SM[(1 * 2 + cur) * 4096]);

        short8 a[4], bb[4];
#pragma unroll
        for (int mt = 0; mt < 4; ++mt)
            a[mt] = *reinterpret_cast<const short8*>(&At[wm * 64 + mt * 16 + lc][quad * 8]);
#pragma unroll
        for (int nt = 0; nt < 4; ++nt)
            bb[nt] = *reinterpret_cast<const short8*>(&Bt[wn * 64 + nt * 16 + lc][quad * 8]);
#pragma unroll
        for (int mt = 0; mt < 4; ++mt)
#pragma unroll
            for (int nt = 0; nt < 4; ++nt)
                acc[mt][nt] = __builtin_amdgcn_mfma_f32_16x16x32_f16(
                    a[mt], bb[nt], acc[mt][nt], 0, 0, 0);

        __syncthreads();
    }

#pragma unroll
    for (int mt = 0; mt < 4; ++mt) {
#pragma unroll
        for (int r = 0; r < 4; ++r) {
            const int o  = ob + wm * 64 + mt * 16 + quad * 4 + r;
            const float bi = bo[o];
#pragma unroll
            for (int nt = 0; nt < 4; ++nt) {
                const int l = lb + wn * 64 + nt * 16 + lc;
                Y[((size_t)b * C_ + o) * L_ + l] = acc[mt][nt][r] + bi;
            }
        }
    }
}

// ---------------------------------------------------------------------------
extern "C" void kernel_launch(void* const* d_in, const int* in_sizes, int n_in,
                              void* d_out, int out_size, void* d_ws, size_t ws_size,
                              hipStream_t stream)
{
    const float* x   = (const float*)d_in[0];
    const float* Wq  = (const float*)d_in[1];
    const float* bq  = (const float*)d_in[2];
    const float* Wk  = (const float*)d_in[3];
    const float* bk  = (const float*)d_in[4];
    const float* Wv  = (const float*)d_in[5];
    const float* bv  = (const float*)d_in[6];
    const float* Wo  = (const float*)d_in[7];
    const float* bo  = (const float*)d_in[8];
    const float* erk = (const float*)d_in[9];
    const float* erv = (const float*)d_in[10];

    char* ws = (char*)d_ws;
    const size_t MB = 1024u * 1024u;
    unsigned short* xT      = (unsigned short*)(ws);             // 8 MB
    unsigned short* Qb      = (unsigned short*)(ws + 8 * MB);    // 8 MB (B,H,L,Dh)
    unsigned short* Kb      = (unsigned short*)(ws + 16 * MB);   // 8 MB (B,H,L,Dh)
    unsigned short* Vc      = (unsigned short*)(ws + 24 * MB);   // 8 MB (B,C,L)
    unsigned short* AOh     = (unsigned short*)(ws + 32 * MB);   // 8 MB f16 (B,L,C)
    unsigned short* Wqkv_hi = (unsigned short*)(ws + 40 * MB);   // 1.5 MB
    unsigned short* Wo_h    = (unsigned short*)(ws + 42 * MB);   // 0.5 MB f16
    float*          bqkv    = (float*)(ws + 43 * MB);            // 6 KB

    prep_transpose_kernel<<<4352, 256, 0, stream>>>(
        x, Wq, Wk, Wv, Wo, bq, bk, bv, xT, Wqkv_hi, Wo_h, bqkv);
    qkv_gemm_kernel<<<dim3(L_ / 128, 12, B_), 256, 0, stream>>>(
        Wqkv_hi, bqkv, xT, Qb, Kb, Vc);
    attn_kernel15<<<dim3(64, 8), 256, 0, stream>>>(
        Qb, Kb, Vc, erk, erv, AOh);
    out_gemm_kernel<<<dim3(L_ / 128, C_ / 128, B_), 256, 0, stream>>>(
        Wo_h, bo, AOh, (float*)d_out);
}

// Round 14
// 159.233 us; speedup vs baseline: 1.0160x; 1.0160x over previous
//
#include <hip/hip_runtime.h>
#include <math.h>

#define B_  8
#define H_  8
#define C_  512
#define L_  1024
#define DH  64
#define WIN 4

typedef __attribute__((ext_vector_type(8))) short short8;
typedef __attribute__((ext_vector_type(4))) float floatx4;

__device__ __forceinline__ unsigned short f2bf(float f) {
    unsigned int u = __float_as_uint(f);
    u = u + 0x7FFFu + ((u >> 16) & 1u);     // RNE
    return (unsigned short)(u >> 16);
}
__device__ __forceinline__ float bf2f(unsigned short h) {
    return __uint_as_float(((unsigned int)h) << 16);
}
__device__ __forceinline__ unsigned short f2h(float f) {
    _Float16 h = (_Float16)f;
    return *reinterpret_cast<unsigned short*>(&h);
}

// async global->LDS, 16B per lane; dest = wave-uniform base + lane*16
__device__ __forceinline__ void gload_lds16(const void* g, void* l) {
    __builtin_amdgcn_global_load_lds(
        (const __attribute__((address_space(1))) void*)g,
        (__attribute__((address_space(3))) void*)l, 16, 0, 0);
}

// ---------------------------------------------------------------------------
// Merged prep + transpose.
// Blocks [0,4096): x (B,C,L) fp32 -> xT bf16 (B,L,C), 32x32 LDS transpose.
// Blocks [4096,4352): W conversions + bias pack.
// ---------------------------------------------------------------------------
__global__ __launch_bounds__(256) void prep_transpose_kernel(
    const float* __restrict__ x,
    const float* __restrict__ Wq, const float* __restrict__ Wk,
    const float* __restrict__ Wv, const float* __restrict__ Wo,
    const float* __restrict__ bq, const float* __restrict__ bk,
    const float* __restrict__ bv,
    unsigned short* __restrict__ xT,
    unsigned short* __restrict__ Wqkv_hi,
    unsigned short* __restrict__ Wo_h,
    float* __restrict__ bqkv)
{
    __shared__ float tile[32][33];
    const int bid = blockIdx.x;
    const int t   = threadIdx.x;

    if (bid < 4096) {
        const int b  = bid >> 9;
        const int cb = ((bid >> 5) & 15) * 32;
        const int lb = (bid & 31) * 32;
        {
            const int l = t & 31, c0 = t >> 5;
#pragma unroll
            for (int p = 0; p < 4; ++p) {
                const int c = c0 + 8 * p;
                tile[c][l] = x[((size_t)b * C_ + cb + c) * L_ + lb + l];
            }
        }
        __syncthreads();
        {
            const int c = t & 31, l0 = t >> 5;
#pragma unroll
            for (int p = 0; p < 4; ++p) {
                const int l = l0 + 8 * p;
                xT[((size_t)b * L_ + lb + l) * C_ + cb + c] = f2bf(tile[c][l]);
            }
        }
    } else {
        const int i = (bid - 4096) * 256 + t;   // 65536 float4 slots
        float4 v; ushort4 h;

        v = ((const float4*)Wq)[i];
        h.x = f2bf(v.x); h.y = f2bf(v.y); h.z = f2bf(v.z); h.w = f2bf(v.w);
        ((ushort4*)Wqkv_hi)[i] = h;

        v = ((const float4*)Wk)[i];
        h.x = f2bf(v.x); h.y = f2bf(v.y); h.z = f2bf(v.z); h.w = f2bf(v.w);
        ((ushort4*)Wqkv_hi)[65536 + i] = h;

        v = ((const float4*)Wv)[i];
        h.x = f2bf(v.x); h.y = f2bf(v.y); h.z = f2bf(v.z); h.w = f2bf(v.w);
        ((ushort4*)Wqkv_hi)[131072 + i] = h;

        v = ((const float4*)Wo)[i];
        h.x = f2h(v.x); h.y = f2h(v.y); h.z = f2h(v.z); h.w = f2h(v.w);
        ((ushort4*)Wo_h)[i] = h;

        if (i < 512)       bqkv[i] = bq[i];
        else if (i < 1024) bqkv[i] = bk[i - 512];
        else if (i < 1536) bqkv[i] = bv[i - 1024];
    }
}

// ---------------------------------------------------------------------------
// Fused QKV GEMM v5: BK=64 (8 K-steps instead of 16 — halves the
// vmcnt(0)+barrier drain count, ~300-500 cyc each per m135, and doubles the
// per-step MFMA run to 32 for better issue overlap).  Per-K staging/read
// traffic unchanged; ds_read b128 is at the 1024B/wave LDS floor either
// way (m134), so no swizzle needed.  LDS = 4 x [128][64] = 64 KB exactly
// (2 blocks/CU, same as attn).  Wave w stages rows [w*32,w*32+32) via 4
// gloads of 8 rows; dest = chunk base + lane*16B (linear: (l>>3)*64+(l&7)*8
// shorts = l*8).  Epilogue sT[128][144] (18432 shorts) aliases SM.
// ---------------------------------------------------------------------------
__global__ __launch_bounds__(256) void qkv_gemm_kernel(
    const unsigned short* __restrict__ Wh, const float* __restrict__ bqkv,
    const unsigned short* __restrict__ xT,
    unsigned short* __restrict__ Qb, unsigned short* __restrict__ Kb,
    unsigned short* __restrict__ Vc)
{
    __shared__ __align__(16) unsigned short SM[32768];  // A0,A1,B0,B1 x [128][64]

    const int b   = blockIdx.z;
    const int oB  = blockIdx.y * 128;
    const int mat = oB >> 9;                // 0=Q,1=K,2=V
    const int ob  = oB & 511;
    const int lb  = blockIdx.x * 128;
    const int t  = threadIdx.x;
    const int w = t >> 6, lane = t & 63, quad = lane >> 4, lc = lane & 15;
    const int wm = w >> 1, wn = w & 1;

    const unsigned short* Wm = Wh + (size_t)mat * C_ * C_;

    floatx4 acc[4][4];
#pragma unroll
    for (int i = 0; i < 4; ++i)
#pragma unroll
        for (int j = 0; j < 4; ++j) acc[i][j] = (floatx4)0.f;

    const int sr8  = lane >> 3;          // row within an 8-row gload chunk
    const int scol = (lane & 7) * 8;     // element col within 64-wide K slab

    // stage one 128x64 slab per operand: wave w rows [w*32, w*32+32)
#define QKV_STAGE(BUF, S) {                                                  \
    const int c0_ = (S) * 64;                                                \
    _Pragma("unroll")                                                        \
    for (int p_ = 0; p_ < 4; ++p_) {                                         \
        const int r0_ = w * 32 + p_ * 8 + sr8;                               \
        gload_lds16(&Wm[(size_t)(ob + r0_) * C_ + c0_ + scol],               \
                    &SM[(0 * 2 + (BUF)) * 8192 + (w * 32 + p_ * 8) * 64]);   \
        gload_lds16(&xT[((size_t)b * L_ + lb + r0_) * C_ + c0_ + scol],      \
                    &SM[(1 * 2 + (BUF)) * 8192 + (w * 32 + p_ * 8) * 64]);   \
    }                                                                        \
}

    QKV_STAGE(0, 0)
    __syncthreads();

    for (int s = 0; s < 8; ++s) {
        const int cur = s & 1;
        if (s < 7) QKV_STAGE(1 - cur, s + 1)

        const unsigned short (*At)[64] =
            reinterpret_cast<const unsigned short (*)[64]>(&SM[(0 * 2 + cur) * 8192]);
        const unsigned short (*Bt)[64] =
            reinterpret_cast<const unsigned short (*)[64]>(&SM[(1 * 2 + cur) * 8192]);

#pragma unroll
        for (int kk = 0; kk < 2; ++kk) {
            short8 a[4], bb[4];
#pragma unroll
            for (int mt = 0; mt < 4; ++mt)
                a[mt] = *reinterpret_cast<const short8*>(
                    &At[wm * 64 + mt * 16 + lc][kk * 32 + quad * 8]);
#pragma unroll
            for (int nt = 0; nt < 4; ++nt)
                bb[nt] = *reinterpret_cast<const short8*>(
                    &Bt[wn * 64 + nt * 16 + lc][kk * 32 + quad * 8]);
#pragma unroll
            for (int mt = 0; mt < 4; ++mt)
#pragma unroll
                for (int nt = 0; nt < 4; ++nt)
                    acc[mt][nt] = __builtin_amdgcn_mfma_f32_16x16x32_bf16(
                        a[mt], bb[nt], acc[mt][nt], 0, 0, 0);
        }

        __syncthreads();   // drains vmcnt(0): next slab complete; reads retired
    }

    if (mat == 2) {
#pragma unroll
        for (int mt = 0; mt < 4; ++mt) {
#pragma unroll
            for (int r = 0; r < 4; ++r) {
                const int o  = ob + wm * 64 + mt * 16 + quad * 4 + r;
                const float bi = bqkv[1024 + o];
#pragma unroll
                for (int nt = 0; nt < 4; ++nt) {
                    const int l = lb + wn * 64 + nt * 16 + lc;
                    Vc[((size_t)b * C_ + o) * L_ + l] = f2bf(acc[mt][nt][r] + bi);
                }
            }
        }
    } else {
        const float scale = (mat == 0) ? 0.125f : 1.0f;
        unsigned short* dst = (mat == 0) ? Qb : Kb;
        unsigned short (*sT)[144] =
            reinterpret_cast<unsigned short (*)[144]>(&SM[0]);

#pragma unroll
        for (int mt = 0; mt < 4; ++mt) {
#pragma unroll
            for (int r = 0; r < 4; ++r) {
                const int o  = ob + wm * 64 + mt * 16 + quad * 4 + r;
                const float bi = bqkv[mat * 512 + o];
                const int d  = mt * 16 + quad * 4 + r;
#pragma unroll
                for (int nt = 0; nt < 4; ++nt) {
                    const int l = wn * 64 + nt * 16 + lc;
                    sT[l][wm * 72 + d] = f2bf((acc[mt][nt][r] + bi) * scale);
                }
            }
        }
        __syncthreads();
        {
            const int l = t >> 1, hf = t & 1;
#pragma unroll
            for (int h01 = 0; h01 < 2; ++h01) {
                const int hgl = (ob >> 6) + h01;
                const size_t o = (((size_t)b * H_ + hgl) * L_ + lb + l) * DH + hf * 32;
                const int cbase = h01 * 72 + hf * 32;
                uint4 v0 = *reinterpret_cast<const uint4*>(&sT[l][cbase]);
                uint4 v1 = *reinterpret_cast<const uint4*>(&sT[l][cbase + 8]);
                uint4 v2 = *reinterpret_cast<const uint4*>(&sT[l][cbase + 16]);
                uint4 v3 = *reinterpret_cast<const uint4*>(&sT[l][cbase + 24]);
                *reinterpret_cast<uint4*>(&dst[o])      = v0;
                *reinterpret_cast<uint4*>(&dst[o + 8])  = v1;
                *reinterpret_cast<uint4*>(&dst[o + 16]) = v2;
                *reinterpret_cast<uint4*>(&dst[o + 24]) = v3;
            }
        }
    }
}

// ---------------------------------------------------------------------------
// Attention v15 (unchanged — measured best): v13a 2-group + s_setprio.
// ---------------------------------------------------------------------------
__global__ __launch_bounds__(256, 2) void attn_kernel15(
    const unsigned short* __restrict__ Qb,   // bf16 (B,H,L,Dh), pre-scaled
    const unsigned short* __restrict__ Kb,   // bf16 (B,H,L,Dh)
    const unsigned short* __restrict__ Vc,   // bf16 (B,C,L)
    const float* __restrict__ erel_k, const float* __restrict__ erel_v,
    unsigned short* __restrict__ AOh)        // f16 (B,L,C)
{
    __shared__ __align__(16) unsigned short kst[2][64][68];   // 17408 B
    __shared__ __align__(16) unsigned short vst[2][64][68];   // 17408 B
    __shared__ __align__(16) unsigned short Pl[4][2][16][68]; // 17408 B
    __shared__ float rs[128][9];                              //  4608 B
    __shared__ float rv[128][9];                              //  4608 B

    const int t  = threadIdx.x;
    const int bh = blockIdx.x;          // 0..63  (id%8==h -> XCD L2 locality)
    const int rt = blockIdx.y;          // 0..7
    const int b = bh >> 3, h = bh & 7;
    const int w = t >> 6, lane = t & 63, quad = lane >> 4, lc = lane & 15;
    const int rowB = rt * 128 + w * 32; // wave's 32 rows; group g: rowB+g*16

    const size_t qkBase = (size_t)bh * L_ * DH;
    const size_t vBase  = ((size_t)b * C_ + h * DH) * L_;

    for (int i = lane; i < 32 * 9; i += 64) rv[w * 32 + i / 9][i % 9] = 0.f;

    // Q A-fragments for both groups
    short8 af0[2], af1[2];
#pragma unroll
    for (int kk = 0; kk < 2; ++kk) {
        af0[kk] = *reinterpret_cast<const short8*>(
            &Qb[qkBase + (size_t)(rowB + lc) * DH + kk * 32 + quad * 8]);
        af1[kk] = *reinterpret_cast<const short8*>(
            &Qb[qkBase + (size_t)(rowB + 16 + lc) * DH + kk * 32 + quad * 8]);
    }

    // rel-k scores via MFMA (bfr built once, shared by both groups)
    {
        floatx4 rsa0 = (floatx4)0.f, rsa1 = (floatx4)0.f;
        const int drow = (lc < 9) ? lc : 8;
#pragma unroll
        for (int kk = 0; kk < 2; ++kk) {
            short8 bfr;
#pragma unroll
            for (int i = 0; i < 8; ++i)
                bfr[i] = (short)f2bf(erel_k[drow * 64 + kk * 32 + quad * 8 + i]);
            rsa0 = __builtin_amdgcn_mfma_f32_16x16x32_bf16(af0[kk], bfr, rsa0, 0, 0, 0);
            rsa1 = __builtin_amdgcn_mfma_f32_16x16x32_bf16(af1[kk], bfr, rsa1, 0, 0, 0);
        }
        if (lc < 9) {
#pragma unroll
            for (int r = 0; r < 4; ++r) {
                rs[w * 32 + quad * 4 + r][lc]      = rsa0[r];
                rs[w * 32 + 16 + quad * 4 + r][lc] = rsa1[r];
            }
        }
    }

    // stage tile 0 (256 thr: 2 uint4 per thread per array covers 64x64)
    const int jr = t >> 2, jcE = (t & 3) * 16;
    *reinterpret_cast<uint4*>(&kst[0][jr][jcE]) =
        *reinterpret_cast<const uint4*>(&Kb[qkBase + (size_t)jr * DH + jcE]);
    *reinterpret_cast<uint4*>(&kst[0][jr][jcE + 8]) =
        *reinterpret_cast<const uint4*>(&Kb[qkBase + (size_t)jr * DH + jcE + 8]);
    *reinterpret_cast<uint4*>(&vst[0][jr][jcE]) =
        *reinterpret_cast<const uint4*>(&Vc[vBase + (size_t)jr * L_ + jcE]);
    *reinterpret_cast<uint4*>(&vst[0][jr][jcE + 8]) =
        *reinterpret_cast<const uint4*>(&Vc[vBase + (size_t)jr * L_ + jcE + 8]);
    __syncthreads();

    short8 ones;
#pragma unroll
    for (int j = 0; j < 8; ++j) ones[j] = (short)0x3F80;

    floatx4 acc_o0[4], acc_o1[4], acc_l0 = (floatx4)0.f, acc_l1 = (floatx4)0.f;
#pragma unroll
    for (int nt = 0; nt < 4; ++nt) { acc_o0[nt] = (floatx4)0.f; acc_o1[nt] = (floatx4)0.f; }

    for (int jt = 0; jt < L_ / 64; ++jt) {
        const int j0  = jt * 64;
        const int cur = jt & 1;

        // register prefetch of next tile (4 uint4)
        uint4 pk0, pk1, pv0, pv1;
        if (jt < L_ / 64 - 1) {
            const int j0n = j0 + 64;
            pk0 = *reinterpret_cast<const uint4*>(
                &Kb[qkBase + (size_t)(j0n + jr) * DH + jcE]);
            pk1 = *reinterpret_cast<const uint4*>(
                &Kb[qkBase + (size_t)(j0n + jr) * DH + jcE + 8]);
            pv0 = *reinterpret_cast<const uint4*>(
                &Vc[vBase + (size_t)jr * L_ + j0n + jcE]);
            pv1 = *reinterpret_cast<const uint4*>(
                &Vc[vBase + (size_t)jr * L_ + j0n + jcE + 8]);
        }

        // S^T = K Q^T for BOTH groups: each kf read feeds 2 MFMAs
        floatx4 s0[4], s1[4];
#pragma unroll
        for (int nt = 0; nt < 4; ++nt) { s0[nt] = (floatx4)0.f; s1[nt] = (floatx4)0.f; }
        __builtin_amdgcn_s_setprio(1);
#pragma unroll
        for (int nt = 0; nt < 4; ++nt)
#pragma unroll
            for (int kk = 0; kk < 2; ++kk) {
                const short8 kf = *reinterpret_cast<const short8*>(
                    &kst[cur][nt * 16 + lc][kk * 32 + quad * 8]);
                s0[nt] = __builtin_amdgcn_mfma_f32_16x16x32_bf16(kf, af0[kk], s0[nt], 0, 0, 0);
                s1[nt] = __builtin_amdgcn_mfma_f32_16x16x32_bf16(kf, af1[kk], s1[nt], 0, 0, 0);
            }
        __builtin_amdgcn_s_setprio(0);

        short8 pf0[2], pf1[2];

        // ---- group 0: bias, exp->Pl[w][0], rv, pf0 ----
        {
            const int rowW = rowB;
            const bool nearD = (j0 <= rowW + 15 + WIN) && (j0 + 63 >= rowW - WIN);
            if (nearD) {
#pragma unroll
                for (int nt = 0; nt < 4; ++nt)
#pragma unroll
                    for (int r = 0; r < 4; ++r) {
                        const int diff = (j0 + nt * 16 + quad * 4 + r) - (rowW + lc);
                        if (diff >= -WIN && diff <= WIN)
                            s0[nt][r] += rs[w * 32 + lc][diff + WIN];
                    }
            }
#pragma unroll
            for (int nt = 0; nt < 4; ++nt) {
                const float e0 = __expf(s0[nt][0]);
                const float e1 = __expf(s0[nt][1]);
                const float e2 = __expf(s0[nt][2]);
                const float e3 = __expf(s0[nt][3]);
                unsigned int u01, u23;
                asm volatile("v_cvt_pk_bf16_f32 %0, %1, %2" : "=v"(u01) : "v"(e0), "v"(e1));
                asm volatile("v_cvt_pk_bf16_f32 %0, %1, %2" : "=v"(u23) : "v"(e2), "v"(e3));
                uint2 pr; pr.x = u01; pr.y = u23;
                *reinterpret_cast<uint2*>(&Pl[w][0][lc][nt * 16 + quad * 4]) = pr;
            }
            if (nearD) {
                for (int idx = lane; idx < 16 * 9; idx += 64) {
                    const int r16 = idx / 9, dr = idx % 9;
                    const int jg = rowW + r16 + dr - WIN;
                    if (jg >= j0 && jg < j0 + 64 && jg >= 0 && jg < L_)
                        rv[w * 32 + r16][dr] += bf2f(Pl[w][0][r16][jg - j0]);
                }
            }
#pragma unroll
            for (int kk = 0; kk < 2; ++kk)
                pf0[kk] = *reinterpret_cast<const short8*>(&Pl[w][0][lc][kk * 32 + quad * 8]);
        }

        // ---- group 1: bias, exp->Pl[w][1] (own buffer), rv, pf1 ----
        {
            const int rowW = rowB + 16;
            const bool nearD = (j0 <= rowW + 15 + WIN) && (j0 + 63 >= rowW - WIN);
            if (nearD) {
#pragma unroll
                for (int nt = 0; nt < 4; ++nt)
#pragma unroll
                    for (int r = 0; r < 4; ++r) {
                        const int diff = (j0 + nt * 16 + quad * 4 + r) - (rowW + lc);
                        if (diff >= -WIN && diff <= WIN)
                            s1[nt][r] += rs[w * 32 + 16 + lc][diff + WIN];
                    }
            }
#pragma unroll
            for (int nt = 0; nt < 4; ++nt) {
                const float e0 = __expf(s1[nt][0]);
                const float e1 = __expf(s1[nt][1]);
                const float e2 = __expf(s1[nt][2]);
                const float e3 = __expf(s1[nt][3]);
                unsigned int u01, u23;
                asm volatile("v_cvt_pk_bf16_f32 %0, %1, %2" : "=v"(u01) : "v"(e0), "v"(e1));
                asm volatile("v_cvt_pk_bf16_f32 %0, %1, %2" : "=v"(u23) : "v"(e2), "v"(e3));
                uint2 pr; pr.x = u01; pr.y = u23;
                *reinterpret_cast<uint2*>(&Pl[w][1][lc][nt * 16 + quad * 4]) = pr;
            }
            if (nearD) {
                for (int idx = lane; idx < 16 * 9; idx += 64) {
                    const int r16 = idx / 9, dr = idx % 9;
                    const int jg = rowW + r16 + dr - WIN;
                    if (jg >= j0 && jg < j0 + 64 && jg >= 0 && jg < L_)
                        rv[w * 32 + 16 + r16][dr] += bf2f(Pl[w][1][r16][jg - j0]);
                }
            }
#pragma unroll
            for (int kk = 0; kk < 2; ++kk)
                pf1[kk] = *reinterpret_cast<const short8*>(&Pl[w][1][lc][kk * 32 + quad * 8]);
        }

        // row sums + PV via MFMA (prioritized cluster)
        __builtin_amdgcn_s_setprio(1);
#pragma unroll
        for (int kk = 0; kk < 2; ++kk) {
            acc_l0 = __builtin_amdgcn_mfma_f32_16x16x32_bf16(pf0[kk], ones, acc_l0, 0, 0, 0);
            acc_l1 = __builtin_amdgcn_mfma_f32_16x16x32_bf16(pf1[kk], ones, acc_l1, 0, 0, 0);
        }
#pragma unroll
        for (int nt = 0; nt < 4; ++nt)
#pragma unroll
            for (int kk = 0; kk < 2; ++kk) {
                const short8 vf = *reinterpret_cast<const short8*>(
                    &vst[cur][nt * 16 + lc][kk * 32 + quad * 8]);
                acc_o0[nt] = __builtin_amdgcn_mfma_f32_16x16x32_bf16(pf0[kk], vf, acc_o0[nt], 0, 0, 0);
                acc_o1[nt] = __builtin_amdgcn_mfma_f32_16x16x32_bf16(pf1[kk], vf, acc_o1[nt], 0, 0, 0);
            }
        __builtin_amdgcn_s_setprio(0);

        // commit prefetched tile, then sync
        if (jt < L_ / 64 - 1) {
            *reinterpret_cast<uint4*>(&kst[1 - cur][jr][jcE])     = pk0;
            *reinterpret_cast<uint4*>(&kst[1 - cur][jr][jcE + 8]) = pk1;
            *reinterpret_cast<uint4*>(&vst[1 - cur][jr][jcE])     = pv0;
            *reinterpret_cast<uint4*>(&vst[1 - cur][jr][jcE + 8]) = pv1;
        }
        __syncthreads();
    }

    // epilogue group 0: rel-v term, normalize, transpose via Pl[w][0], store
    {
#pragma unroll
        for (int nt = 0; nt < 4; ++nt) {
            const int d = nt * 16 + lc;
            float ev[9];
#pragma unroll
            for (int dr = 0; dr < 9; ++dr) ev[dr] = erel_v[dr * 64 + d];
#pragma unroll
            for (int r = 0; r < 4; ++r) {
                const int rloc = w * 32 + quad * 4 + r;
                float v = acc_o0[nt][r];
#pragma unroll
                for (int dr = 0; dr < 9; ++dr) v += rv[rloc][dr] * ev[dr];
                Pl[w][0][quad * 4 + r][nt * 16 + lc] = f2h(v / acc_l0[r]);
            }
        }
        const int row = lane >> 2, ds8 = (lane & 3) * 16;
        const uint4 q0 = *reinterpret_cast<const uint4*>(&Pl[w][0][row][ds8]);
        const uint4 q1 = *reinterpret_cast<const uint4*>(&Pl[w][0][row][ds8 + 8]);
        const size_t o = ((size_t)b * L_ + rowB + row) * C_ + h * 64 + ds8;
        *reinterpret_cast<uint4*>(&AOh[o])     = q0;
        *reinterpret_cast<uint4*>(&AOh[o + 8]) = q1;
    }
    // epilogue group 1
    {
#pragma unroll
        for (int nt = 0; nt < 4; ++nt) {
            const int d = nt * 16 + lc;
            float ev[9];
#pragma unroll
            for (int dr = 0; dr < 9; ++dr) ev[dr] = erel_v[dr * 64 + d];
#pragma unroll
            for (int r = 0; r < 4; ++r) {
                const int rloc = w * 32 + 16 + quad * 4 + r;
                float v = acc_o1[nt][r];
#pragma unroll
                for (int dr = 0; dr < 9; ++dr) v += rv[rloc][dr] * ev[dr];
                Pl[w][1][quad * 4 + r][nt * 16 + lc] = f2h(v / acc_l1[r]);
            }
        }
        const int row = lane >> 2, ds8 = (lane & 3) * 16;
        const uint4 q0 = *reinterpret_cast<const uint4*>(&Pl[w][1][row][ds8]);
        const uint4 q1 = *reinterpret_cast<const uint4*>(&Pl[w][1][row][ds8 + 8]);
        const size_t o = ((size_t)b * L_ + rowB + 16 + row) * C_ + h * 64 + ds8;
        *reinterpret_cast<uint4*>(&AOh[o])     = q0;
        *reinterpret_cast<uint4*>(&AOh[o + 8]) = q1;
    }
}

// ---------------------------------------------------------------------------
// Output projection v5: 128x128 tile (v4 structure) + BK=64 (same transform
// as qkv v5: 8 K-steps, half the barrier drains, 32-MFMA steps).
// LDS = 4 x [128][64] = 64 KB.  f16 MFMA, direct coalesced fp32 epilogue.
// ---------------------------------------------------------------------------
__global__ __launch_bounds__(256) void out_gemm_kernel(
    const unsigned short* __restrict__ Wh,   // f16 512x512
    const float* __restrict__ bo,
    const unsigned short* __restrict__ Ah,   // f16 (B,L,C)
    float* __restrict__ Y)
{
    __shared__ __align__(16) unsigned short SM[32768];  // A0,A1,B0,B1 x [128][64]

    const int b  = blockIdx.z;
    const int ob = blockIdx.y * 128;
    const int lb = blockIdx.x * 128;
    const int t  = threadIdx.x;
    const int w = t >> 6, lane = t & 63, quad = lane >> 4, lc = lane & 15;
    const int wm = w >> 1, wn = w & 1;

    floatx4 acc[4][4];
#pragma unroll
    for (int i = 0; i < 4; ++i)
#pragma unroll
        for (int j = 0; j < 4; ++j) acc[i][j] = (floatx4)0.f;

    const int sr8  = lane >> 3;
    const int scol = (lane & 7) * 8;

#define OG_STAGE(BUF, S) {                                                   \
    const int c0_ = (S) * 64;                                                \
    _Pragma("unroll")                                                        \
    for (int p_ = 0; p_ < 4; ++p_) {                                         \
        const int r0_ = w * 32 + p_ * 8 + sr8;                               \
        gload_lds16(&Wh[(size_t)(ob + r0_) * C_ + c0_ + scol],               \
                    &SM[(0 * 2 + (BUF)) * 8192 + (w * 32 + p_ * 8) * 64]);   \
        gload_lds16(&Ah[((size_t)b * L_ + lb + r0_) * C_ + c0_ + scol],      \
                    &SM[(1 * 2 + (BUF)) * 8192 + (w * 32 + p_ * 8) * 64]);   \
    }                                                                        \
}

    OG_STAGE(0, 0)
    __syncthreads();

    for (int s = 0; s < 8; ++s) {
        const int cur = s & 1;
        if (s < 7) OG_STAGE(1 - cur, s + 1)

        const unsigned short (*At)[64] =
            reinterpret_cast<const unsigned short (*)[64]>(&SM[(0 * 2 + cur) * 8192]);
        const unsigned short (*Bt)[64] =
            reinterpret_cast<const unsigned short (*)[64]>(&SM[(1 * 2 + cur) * 8192]);

#pragma unroll
        for (int kk = 0; kk < 2; ++kk) {
            short8 a[4], bb[4];
#pragma unroll
            for (int mt = 0; mt < 4; ++mt)
                a[mt] = *reinterpret_cast<const short8*>(
                    &At[wm * 64 + mt * 16 + lc][kk * 32 + quad * 8]);
#pragma unroll
            for (int nt = 0; nt < 4; ++nt)
                bb[nt] = *reinterpret_cast<const short8*>(
                    &Bt[wn * 64 + nt * 16 + lc][kk * 32 + quad * 8]);
#pragma unroll
            for (int mt = 0; mt < 4; ++mt)
#pragma unroll
                for (int nt = 0; nt < 4; ++nt)
                    acc[mt][nt] = __builtin_amdgcn_mfma_f32_16x16x32_f16(
                        a[mt], bb[nt], acc[mt][nt], 0, 0, 0);
        }

        __syncthreads();
    }

#pragma unroll
    for (int mt = 0; mt < 4; ++mt) {
#pragma unroll
        for (int r = 0; r < 4; ++r) {
            const int o  = ob + wm * 64 + mt * 16 + quad * 4 + r;
            const float bi = bo[o];
#pragma unroll
            for (int nt = 0; nt < 4; ++nt) {
                const int l = lb + wn * 64 + nt * 16 + lc;
                Y[((size_t)b * C_ + o) * L_ + l] = acc[mt][nt][r] + bi;
            }
        }
    }
}

// ---------------------------------------------------------------------------
extern "C" void kernel_launch(void* const* d_in, const int* in_sizes, int n_in,
                              void* d_out, int out_size, void* d_ws, size_t ws_size,
                              hipStream_t stream)
{
    const float* x   = (const float*)d_in[0];
    const float* Wq  = (const float*)d_in[1];
    const float* bq  = (const float*)d_in[2];
    const float* Wk  = (const float*)d_in[3];
    const float* bk  = (const float*)d_in[4];
    const float* Wv  = (const float*)d_in[5];
    const float* bv  = (const float*)d_in[6];
    const float* Wo  = (const float*)d_in[7];
    const float* bo  = (const float*)d_in[8];
    const float* erk = (const float*)d_in[9];
    const float* erv = (const float*)d_in[10];

    char* ws = (char*)d_ws;
    const size_t MB = 1024u * 1024u;
    unsigned short* xT      = (unsigned short*)(ws);             // 8 MB
    unsigned short* Qb      = (unsigned short*)(ws + 8 * MB);    // 8 MB (B,H,L,Dh)
    unsigned short* Kb      = (unsigned short*)(ws + 16 * MB);   // 8 MB (B,H,L,Dh)
    unsigned short* Vc      = (unsigned short*)(ws + 24 * MB);   // 8 MB (B,C,L)
    unsigned short* AOh     = (unsigned short*)(ws + 32 * MB);   // 8 MB f16 (B,L,C)
    unsigned short* Wqkv_hi = (unsigned short*)(ws + 40 * MB);   // 1.5 MB
    unsigned short* Wo_h    = (unsigned short*)(ws + 42 * MB);   // 0.5 MB f16
    float*          bqkv    = (float*)(ws + 43 * MB);            // 6 KB

    prep_transpose_kernel<<<4352, 256, 0, stream>>>(
        x, Wq, Wk, Wv, Wo, bq, bk, bv, xT, Wqkv_hi, Wo_h, bqkv);
    qkv_gemm_kernel<<<dim3(L_ / 128, 12, B_), 256, 0, stream>>>(
        Wqkv_hi, bqkv, xT, Qb, Kb, Vc);
    attn_kernel15<<<dim3(64, 8), 256, 0, stream>>>(
        Qb, Kb, Vc, erk, erv, AOh);
    out_gemm_kernel<<<dim3(L_ / 128, C_ / 128, B_), 256, 0, stream>>>(
        Wo_h, bo, AOh, (float*)d_out);
}